// Round 2
// baseline (2315.075 us; speedup 1.0000x reference)
//
#include <hip/hip_runtime.h>
#include <hip/hip_bf16.h>
#include <cstdint>
#include <cstddef>

#define B_SZ 8192
#define D_SZ 1024
#define H_SZ 2048
#define S_SZ 4
#define C_SZ 1000
#define N1   16384            // S*2H
#define EPSF 1e-8f

typedef __attribute__((ext_vector_type(4))) float f32x4;
typedef __attribute__((ext_vector_type(8))) short s16x8;

static __device__ __forceinline__ float bf2f(unsigned short u){
  union { unsigned int i; float f; } c; c.i = ((unsigned int)u) << 16; return c.f;
}
static __device__ __forceinline__ unsigned short f2bf(float f){
  union { float f; unsigned int i; } c; c.f = f;
  unsigned int x = c.i;
  return (unsigned short)((x + 0x7FFFu + ((x >> 16) & 1u)) >> 16);
}

// ---------------- conversions ----------------
__global__ __launch_bounds__(256) void cvt_bf16(const float* __restrict__ src,
                                                unsigned short* __restrict__ dst, int n4){
  int i = blockIdx.x * 256 + threadIdx.x;
  if (i >= n4) return;
  float4 v = ((const float4*)src)[i];
  ushort4 o; o.x = f2bf(v.x); o.y = f2bf(v.y); o.z = f2bf(v.z); o.w = f2bf(v.w);
  ((ushort4*)dst)[i] = o;
}

__global__ __launch_bounds__(256) void transpose_wc(const float* __restrict__ Wc,
                                                    float* __restrict__ WcT){
  int idx = blockIdx.x * 256 + threadIdx.x;
  if (idx >= H_SZ * C_SZ) return;
  int h = idx / C_SZ, c = idx - h * C_SZ;
  WcT[idx] = Wc[(size_t)c * H_SZ + h];   // WcT: H x C
}

// ---------------- MFMA GEMM: C = epilogue(A(MxK) * B(NxK)^T) ----------------
// MODE 0: Gaussian: G = bf16(exp(-(acc+bnet[n])^2))
// MODE 1: gate: g=sigmoid(acc+bg[n]); supR*=g; supI*=g (bf16, in place)
#define BM 128
#define BN 128
#define BK 64
#define RS 72   // LDS row stride (bf16 elems): 144B rows -> conflict-free b128 reads

template<int MODE>
__global__ __launch_bounds__(256) void gemm_bt(
    const unsigned short* __restrict__ A,   // M x K bf16
    const unsigned short* __restrict__ Bm,  // N x K bf16
    int M, int N, int K,
    const float* __restrict__ bias,         // length N
    unsigned short* __restrict__ Gout,      // MODE 0 out (M x N bf16)
    unsigned short* __restrict__ supR,      // MODE 1 inout bf16
    unsigned short* __restrict__ supI)
{
  __shared__ __align__(16) unsigned short lds_a[BM*RS];
  __shared__ __align__(16) unsigned short lds_b[BN*RS];
  const int tid = threadIdx.x;
  const int lane = tid & 63;
  const int wid = tid >> 6;
  const int wm = wid >> 1, wn = wid & 1;
  const int lr = lane & 15, lg = lane >> 4;
  const int m0 = blockIdx.y * BM, n0 = blockIdx.x * BN;

  f32x4 acc[4][4];
  #pragma unroll
  for (int i = 0; i < 4; i++)
    #pragma unroll
    for (int j = 0; j < 4; j++){ f32x4 z = {0.f,0.f,0.f,0.f}; acc[i][j] = z; }

  const int nkt = K / BK;
  for (int kt = 0; kt < nkt; ++kt){
    uint4 ra[4], rb[4];
    #pragma unroll
    for (int i = 0; i < 4; i++){
      int c = i*256 + tid;
      int row = c >> 3, slot = c & 7;
      ra[i] = *(const uint4*)&A [(size_t)(m0+row)*K + kt*BK + slot*8];
      rb[i] = *(const uint4*)&Bm[(size_t)(n0+row)*K + kt*BK + slot*8];
    }
    __syncthreads();                 // previous compute done reading LDS
    #pragma unroll
    for (int i = 0; i < 4; i++){
      int c = i*256 + tid;
      int row = c >> 3, slot = c & 7;
      *(uint4*)&lds_a[row*RS + slot*8] = ra[i];
      *(uint4*)&lds_b[row*RS + slot*8] = rb[i];
    }
    __syncthreads();
    #pragma unroll
    for (int kk = 0; kk < 2; ++kk){
      s16x8 af[4], bfr[4];
      #pragma unroll
      for (int mi = 0; mi < 4; mi++){
        int row = wm*64 + mi*16 + lr;
        af[mi] = *(const s16x8*)&lds_a[row*RS + kk*32 + lg*8];
      }
      #pragma unroll
      for (int ni = 0; ni < 4; ni++){
        int row = wn*64 + ni*16 + lr;
        bfr[ni] = *(const s16x8*)&lds_b[row*RS + kk*32 + lg*8];
      }
      #pragma unroll
      for (int mi = 0; mi < 4; mi++)
        #pragma unroll
        for (int ni = 0; ni < 4; ni++)
          acc[mi][ni] = __builtin_amdgcn_mfma_f32_16x16x32_bf16(af[mi], bfr[ni], acc[mi][ni], 0, 0, 0);
    }
  }

  // epilogue: D mapping col=lane&15, row=(lane>>4)*4+reg
  #pragma unroll
  for (int mi = 0; mi < 4; mi++){
    #pragma unroll
    for (int ni = 0; ni < 4; ni++){
      int n = n0 + wn*64 + ni*16 + lr;
      float bn = bias[n];
      #pragma unroll
      for (int r = 0; r < 4; r++){
        int m = m0 + wm*64 + mi*16 + lg*4 + r;
        float v = acc[mi][ni][r];
        if (MODE == 0){
          float z = v + bn;
          Gout[(size_t)m*N + n] = f2bf(expf(-z*z));
        } else {
          float g = 1.0f / (1.0f + expf(-(v + bn)));
          size_t idx = (size_t)m*N + n;
          float rr = bf2f(supR[idx])*g, ii = bf2f(supI[idx])*g;
          supR[idx] = f2bf(rr); supI[idx] = f2bf(ii);
        }
      }
    }
  }
}

// ---------------- stage-1 epilogue: normalization + superposition ----------------
template<int NR>
__device__ __forceinline__ void breduce(const float* vals, float* red,
                                        float* outp, int lane, int wid, int tid){
  #pragma unroll
  for (int j = 0; j < NR; j++){
    float x = vals[j];
    #pragma unroll
    for (int off = 32; off >= 1; off >>= 1) x += __shfl_down(x, off, 64);
    if (lane == 0) red[wid*NR + j] = x;
  }
  __syncthreads();
  if (tid < NR) outp[tid] = red[tid] + red[NR+tid] + red[2*NR+tid] + red[3*NR+tid];
  __syncthreads();
}

__global__ __launch_bounds__(256) void k2_superpose(
  const unsigned short* __restrict__ G, const float* __restrict__ phases,
  unsigned short* __restrict__ supR, unsigned short* __restrict__ supI)
{
  __shared__ float red[36];
  __shared__ float outp[9];
  const int tid = threadIdx.x, lane = tid & 63, wid = tid >> 6;
  const int b = blockIdx.x;              // local row within chunk
  const size_t gbase = (size_t)b * N1;
  const int h0 = tid * 8;

  float av[S_SZ][8], bv[S_SZ][8], nsq[S_SZ];
  #pragma unroll
  for (int s = 0; s < S_SZ; s++){
    s16x8 va = *(const s16x8*)&G[gbase + s*4096 + h0];
    s16x8 vb = *(const s16x8*)&G[gbase + s*4096 + 2048 + h0];
    float accn = 0.f;
    #pragma unroll
    for (int i = 0; i < 8; i++){
      float a  = bf2f((unsigned short)va[i]);
      float bb = bf2f((unsigned short)vb[i]);
      av[s][i] = a; bv[s][i] = bb;
      accn += a*a + bb*bb;
    }
    nsq[s] = accn;
  }
  breduce<4>(nsq, red, outp, lane, wid, tid);

  float fac[S_SZ], cc[S_SZ], sn[S_SZ];
  #pragma unroll
  for (int s = 0; s < S_SZ; s++){
    fac[s] = sqrtf(2.25f / (outp[s] + EPSF));   // PARTIAL_NORM^2 = 2.25
    float ph = phases[s];
    cc[s] = cosf(ph); sn[s] = sinf(ph);
  }
  float re[S_SZ][8], im[S_SZ][8], mr[8];
  #pragma unroll
  for (int i = 0; i < 8; i++) mr[i] = 0.f;
  #pragma unroll
  for (int s = 0; s < S_SZ; s++)
    #pragma unroll
    for (int i = 0; i < 8; i++){
      float r = fac[s]*(av[s][i]*cc[s] - bv[s][i]*sn[s]);
      float q = fac[s]*(av[s][i]*sn[s] + bv[s][i]*cc[s]);
      re[s][i] = r; im[s][i] = q; mr[i] += r;
    }
  #pragma unroll
  for (int i = 0; i < 8; i++) mr[i] *= 0.25f;

  float pv[9];
  { float t = 0.f;
    #pragma unroll
    for (int i = 0; i < 8; i++) t += mr[i]*mr[i];
    pv[0] = t; }
  #pragma unroll
  for (int s = 0; s < S_SZ; s++){
    float t1 = 0.f, t2 = 0.f;
    #pragma unroll
    for (int i = 0; i < 8; i++){ t1 += re[s][i]*re[s][i]; t2 += re[s][i]*mr[i]; }
    pv[1+s] = t1; pv[5+s] = t2;
  }
  breduce<9>(pv, red, outp, lane, wid, tid);

  float mean_norm = sqrtf(outp[0]) + EPSF;
  float w[S_SZ]; float mx = -1e30f;
  #pragma unroll
  for (int s = 0; s < S_SZ; s++){
    float wn = sqrtf(outp[1+s]) + EPSF;
    float csim = outp[5+s] / (wn * mean_norm);
    w[s] = csim; mx = fmaxf(mx, csim);
  }
  float se = 0.f;
  #pragma unroll
  for (int s = 0; s < S_SZ; s++){ w[s] = expf(w[s]-mx); se += w[s]; }
  float invse = 1.f / se;
  #pragma unroll
  for (int s = 0; s < S_SZ; s++) w[s] *= invse;

  s16x8 ro, io;
  #pragma unroll
  for (int i = 0; i < 8; i++){
    float sr = 0.f, si = 0.f;
    #pragma unroll
    for (int s = 0; s < S_SZ; s++){ sr += w[s]*re[s][i]; si += w[s]*im[s][i]; }
    ro[i] = (short)f2bf(sr); io[i] = (short)f2bf(si);
  }
  size_t ob = (size_t)b*H_SZ + h0;
  *(s16x8*)&supR[ob] = ro;
  *(s16x8*)&supI[ob] = io;
}

// ---------------- mag = bf16(sqrt(r^2+i^2+eps)) ----------------
__global__ __launch_bounds__(256) void magcalc(const unsigned short* __restrict__ sR,
                                               const unsigned short* __restrict__ sI,
                                               unsigned short* __restrict__ mag, int n8){
  int i = blockIdx.x*256 + threadIdx.x;
  if (i >= n8) return;
  s16x8 r = *(const s16x8*)&sR[(size_t)i*8];
  s16x8 q = *(const s16x8*)&sI[(size_t)i*8];
  s16x8 o;
  #pragma unroll
  for (int j = 0; j < 8; j++){
    float rf = bf2f((unsigned short)r[j]);
    float qf = bf2f((unsigned short)q[j]);
    o[j] = (short)f2bf(sqrtf(rf*rf + qf*qf + EPSF));
  }
  *(s16x8*)&mag[(size_t)i*8] = o;
}

// ---------------- top-64 + sparse output ----------------
__global__ __launch_bounds__(256) void k4_topk(
  const unsigned short* __restrict__ supR, const unsigned short* __restrict__ supI,
  const float* __restrict__ WcT, const float* __restrict__ bcv,
  float* __restrict__ outg)
{
  __shared__ float msq[H_SZ];
  __shared__ int   redi[4];
  __shared__ int   sel_idx[64];
  __shared__ float sel_p[64];
  __shared__ int   cnt;
  __shared__ float ssum_sh;
  const int tid = threadIdx.x, lane = tid & 63, wid = tid >> 6;
  const int b = blockIdx.x;
  const size_t base = (size_t)b * H_SZ;

  if (tid < 64){ sel_p[tid] = 0.f; sel_idx[tid] = 0; }
  if (tid == 0) cnt = 0;

  float v[8]; unsigned int u[8];
  {
    s16x8 r = *(const s16x8*)&supR[base + tid*8];
    s16x8 q = *(const s16x8*)&supI[base + tid*8];
    #pragma unroll
    for (int i = 0; i < 8; i++){
      float rf = bf2f((unsigned short)r[i]);
      float qf = bf2f((unsigned short)q[i]);
      v[i] = rf*rf + qf*qf;
    }
  }
  #pragma unroll
  for (int i = 0; i < 8; i++){ msq[tid*8+i] = v[i]; u[i] = __float_as_uint(v[i]); }
  __syncthreads();

  // binary search for V = 64th largest value (uint-monotonic for non-negative floats)
  unsigned int lo = 0u, hi = 0xFFFFFFFFu;
  for (int it = 0; it < 32; ++it){
    unsigned int mid = (unsigned int)(((unsigned long long)lo + (unsigned long long)hi + 1ull) >> 1);
    int c = 0;
    #pragma unroll
    for (int i = 0; i < 8; i++) c += (u[i] >= mid) ? 1 : 0;
    #pragma unroll
    for (int off = 32; off >= 1; off >>= 1) c += __shfl_down(c, off, 64);
    if (lane == 0) redi[wid] = c;
    __syncthreads();
    int total = redi[0]+redi[1]+redi[2]+redi[3];
    __syncthreads();
    if (total >= 64) lo = mid; else hi = mid - 1u;
  }
  const unsigned int V = lo;

  int cg = 0;
  #pragma unroll
  for (int i = 0; i < 8; i++) cg += (u[i] > V) ? 1 : 0;
  #pragma unroll
  for (int off = 32; off >= 1; off >>= 1) cg += __shfl_down(cg, off, 64);
  if (lane == 0) redi[wid] = cg;
  __syncthreads();
  const int ng = redi[0]+redi[1]+redi[2]+redi[3];
  const int kfill = 64 - ng;       // >=1 by construction

  #pragma unroll
  for (int i = 0; i < 8; i++){
    if (u[i] > V){
      int ppos = atomicAdd(&cnt, 1);
      if (ppos < 64){ sel_idx[ppos] = tid*8 + i; sel_p[ppos] = v[i]; }
    }
  }
  __syncthreads();
  // fill ties (== V) in ascending index order (jax.lax.top_k tie-break)
  if (wid == 0){
    int taken = 0;
    for (int b2 = 0; b2 < H_SZ; b2 += 64){
      float val = msq[b2 + lane];
      bool eq = (__float_as_uint(val) == V);
      unsigned long long mk = __ballot(eq);
      int pre = __popcll(mk & ((1ull << lane) - 1ull));
      int dst = ng + taken + pre;
      if (eq && dst < 64){
        sel_idx[dst] = b2 + lane;
        sel_p [dst] = val;
      }
      taken += __popcll(mk);
      if (taken >= kfill) break;
    }
  }
  __syncthreads();
  if (wid == 0){
    float xx = sel_p[lane];
    #pragma unroll
    for (int off = 32; off >= 1; off >>= 1) xx += __shfl_down(xx, off, 64);
    if (lane == 0) ssum_sh = xx;
  }
  __syncthreads();
  const float invden = 1.f / (ssum_sh + EPSF);
  if (tid < 64) sel_p[tid] *= invden;
  __syncthreads();

  for (int c = tid; c < C_SZ; c += 256){
    float acc = bcv[c];
    #pragma unroll 8
    for (int k = 0; k < 64; k++) acc += sel_p[k] * WcT[(size_t)sel_idx[k]*C_SZ + c];
    outg[(size_t)b*C_SZ + c] = acc;
  }
}

// ---------------- launch ----------------
extern "C" void kernel_launch(void* const* d_in, const int* in_sizes, int n_in,
                              void* d_out, int out_size, void* d_ws, size_t ws_size,
                              hipStream_t stream){
  (void)in_sizes; (void)n_in; (void)out_size;
  const float* x      = (const float*)d_in[0];
  const float* Wnet   = (const float*)d_in[1];
  const float* bnet   = (const float*)d_in[2];
  const float* phases = (const float*)d_in[3];
  const float* Wg     = (const float*)d_in[4];
  const float* bg     = (const float*)d_in[5];
  const float* Wc     = (const float*)d_in[6];
  const float* bc     = (const float*)d_in[7];
  float* out = (float*)d_out;

  char* p = (char*)d_ws;
  const size_t MB = 1024ull*1024ull;
  // Region R1 (48 MB), two lifetimes:
  //   phase A: xb (16 MB) + Wnetb (32 MB)
  //   phase B: Wgb (8 MB) + WcT (8 MB) + mag (32 MB)
  unsigned short* xb    = (unsigned short*)(p + 0);
  unsigned short* Wnetb = (unsigned short*)(p + 16*MB);
  unsigned short* Wgb   = (unsigned short*)(p + 0);
  float*          WcT   = (float*)(p + 8*MB);
  unsigned short* mag   = (unsigned short*)(p + 16*MB);
  // Persistent bf16 superposition state (64 MB)
  unsigned short* supR  = (unsigned short*)(p + 48*MB);
  unsigned short* supI  = (unsigned short*)(p + 80*MB);
  // G chunk buffer, sized from remaining workspace
  unsigned short* G     = (unsigned short*)(p + 112*MB);

  size_t avail = (ws_size > 112*MB) ? (ws_size - 112*MB) : 0;
  long rows_cap = (long)(avail / ((size_t)N1 * 2));
  int chunk = (int)((rows_cap / BM) * BM);
  if (chunk > B_SZ) chunk = B_SZ;
  if (chunk < BM)   chunk = BM;      // last-ditch; needs ws_size >= ~116 MB

  cvt_bf16<<<(B_SZ*D_SZ/4 + 255)/256, 256, 0, stream>>>(x, xb, B_SZ*D_SZ/4);
  cvt_bf16<<<(N1*D_SZ/4 + 255)/256, 256, 0, stream>>>(Wnet, Wnetb, N1*D_SZ/4);

  for (int b0 = 0; b0 < B_SZ; b0 += chunk){
    int rows = (B_SZ - b0 < chunk) ? (B_SZ - b0) : chunk;
    gemm_bt<0><<<dim3(N1/BN, rows/BM), 256, 0, stream>>>(
        xb + (size_t)b0*D_SZ, Wnetb, rows, N1, D_SZ, bnet, G, nullptr, nullptr);
    k2_superpose<<<rows, 256, 0, stream>>>(
        G, phases, supR + (size_t)b0*H_SZ, supI + (size_t)b0*H_SZ);
  }

  // phase B (overwrites xb/Wnetb region — they are dead now)
  cvt_bf16<<<(H_SZ*H_SZ/4 + 255)/256, 256, 0, stream>>>(Wg, Wgb, H_SZ*H_SZ/4);
  transpose_wc<<<(H_SZ*C_SZ + 255)/256, 256, 0, stream>>>(Wc, WcT);

  magcalc<<<(B_SZ*H_SZ/8)/256, 256, 0, stream>>>(supR, supI, mag, B_SZ*H_SZ/8);
  gemm_bt<1><<<dim3(H_SZ/BN, B_SZ/BM), 256, 0, stream>>>(
      mag, Wgb, B_SZ, H_SZ, H_SZ, bg, nullptr, supR, supI);
  magcalc<<<(B_SZ*H_SZ/8)/256, 256, 0, stream>>>(supR, supI, mag, B_SZ*H_SZ/8);
  gemm_bt<1><<<dim3(H_SZ/BN, B_SZ/BM), 256, 0, stream>>>(
      mag, Wgb, B_SZ, H_SZ, H_SZ, bg, nullptr, supR, supI);

  k4_topk<<<B_SZ, 256, 0, stream>>>(supR, supI, WcT, bc, out);
}

// Round 3
// 1177.315 us; speedup vs baseline: 1.9664x; 1.9664x over previous
//
#include <hip/hip_runtime.h>
#include <hip/hip_bf16.h>
#include <cstdint>
#include <cstddef>

#define B_SZ 8192
#define D_SZ 1024
#define H_SZ 2048
#define S_SZ 4
#define C_SZ 1000
#define N1   16384            // S*2H
#define EPSF 1e-8f

typedef __attribute__((ext_vector_type(4))) float f32x4;
typedef __attribute__((ext_vector_type(8))) short s16x8;

typedef __attribute__((address_space(3))) void lds_void;
typedef const __attribute__((address_space(1))) void glb_void;

static __device__ __forceinline__ void gload16(const void* g, void* l){
  __builtin_amdgcn_global_load_lds((glb_void*)g, (lds_void*)l, 16, 0, 0);
}

static __device__ __forceinline__ float bf2f(unsigned short u){
  union { unsigned int i; float f; } c; c.i = ((unsigned int)u) << 16; return c.f;
}
static __device__ __forceinline__ unsigned short f2bf(float f){
  union { float f; unsigned int i; } c; c.f = f;
  unsigned int x = c.i;
  return (unsigned short)((x + 0x7FFFu + ((x >> 16) & 1u)) >> 16);
}

// ---------------- conversions ----------------
__global__ __launch_bounds__(256) void cvt_bf16(const float* __restrict__ src,
                                                unsigned short* __restrict__ dst, int n4){
  int i = blockIdx.x * 256 + threadIdx.x;
  if (i >= n4) return;
  float4 v = ((const float4*)src)[i];
  ushort4 o; o.x = f2bf(v.x); o.y = f2bf(v.y); o.z = f2bf(v.z); o.w = f2bf(v.w);
  ((ushort4*)dst)[i] = o;
}

__global__ __launch_bounds__(256) void transpose_wc(const float* __restrict__ Wc,
                                                    unsigned short* __restrict__ WcTb){
  int idx = blockIdx.x * 256 + threadIdx.x;
  if (idx >= H_SZ * C_SZ) return;
  int h = idx / C_SZ, c = idx - h * C_SZ;
  WcTb[idx] = f2bf(Wc[(size_t)c * H_SZ + h]);   // WcTb: H x C bf16
}

// ---------------- MFMA GEMM: C = epilogue(A(MxK) * B(NxK)^T) ----------------
// MODE 0: Gaussian: G = bf16(exp(-(acc+bnet[n])^2))
// MODE 1: gate=sigmoid(acc+bg[n]); supR*=gate; supI*=gate; mag=sqrt(r^2+i^2+eps)
#define BM 128
#define BN 128
#define BK 64

template<int MODE>
__global__ __launch_bounds__(256) void gemm_bt(
    const unsigned short* __restrict__ A,   // M x K bf16
    const unsigned short* __restrict__ Bm,  // N x K bf16
    int M, int N, int K,
    const float* __restrict__ bias,         // length N
    unsigned short* __restrict__ Gout,      // MODE 0 out (M x N bf16)
    unsigned short* __restrict__ supR,      // MODE 1 inout bf16
    unsigned short* __restrict__ supI,      // MODE 1 inout bf16
    unsigned short* __restrict__ magout)    // MODE 1 out bf16
{
  __shared__ __align__(16) unsigned short lds[2*BM*BK];   // 32 KB: A tile then B tile
  unsigned short* la = lds;
  unsigned short* lb = lds + BM*BK;
  const int tid = threadIdx.x;
  const int lane = tid & 63;
  const int w = tid >> 6;
  const int wm = w >> 1, wn = w & 1;
  const int lr = lane & 15, lg = lane >> 4;
  const int srow = lane >> 3;            // 0..7
  const int scol = (lane & 7) * 8;       // elem within BK

  // bijective XCD swizzle (m204)
  const int gx = gridDim.x;
  const int nwg = gx * gridDim.y;
  const int bid = blockIdx.y * gx + blockIdx.x;
  const int q = nwg >> 3, rmd = nwg & 7, xcd = bid & 7, lid = bid >> 3;
  const int swz = (xcd < rmd ? xcd*(q+1) : rmd*(q+1) + (xcd-rmd)*q) + lid;
  const int m0 = (swz / gx) * BM;
  const int n0 = (swz % gx) * BN;

  f32x4 acc[4][4];
  #pragma unroll
  for (int i = 0; i < 4; i++)
    #pragma unroll
    for (int j = 0; j < 4; j++){ f32x4 z = {0.f,0.f,0.f,0.f}; acc[i][j] = z; }

  const int nkt = K / BK;
  for (int kt = 0; kt < nkt; ++kt){
    __syncthreads();                      // prev compute done reading LDS
    const unsigned short* ga = A  + (size_t)m0*K + (size_t)kt*BK;
    const unsigned short* gb = Bm + (size_t)n0*K + (size_t)kt*BK;
    #pragma unroll
    for (int i = 0; i < 4; i++){
      int seg = i*4 + w;                  // wave-uniform
      gload16(ga + (size_t)(seg*8 + srow)*K + scol, &la[seg*512]);
      gload16(gb + (size_t)(seg*8 + srow)*K + scol, &lb[seg*512]);
    }
    __syncthreads();                      // implicit vmcnt(0) drain
    #pragma unroll
    for (int kk = 0; kk < 2; ++kk){
      s16x8 af[4], bfr[4];
      #pragma unroll
      for (int mi = 0; mi < 4; mi++)
        af[mi] = *(const s16x8*)&la[(wm*64 + mi*16 + lr)*BK + kk*32 + lg*8];
      #pragma unroll
      for (int ni = 0; ni < 4; ni++)
        bfr[ni] = *(const s16x8*)&lb[(wn*64 + ni*16 + lr)*BK + kk*32 + lg*8];
      #pragma unroll
      for (int mi = 0; mi < 4; mi++)
        #pragma unroll
        for (int ni = 0; ni < 4; ni++)
          acc[mi][ni] = __builtin_amdgcn_mfma_f32_16x16x32_bf16(af[mi], bfr[ni], acc[mi][ni], 0, 0, 0);
    }
  }

  // ---- epilogue: bf16 result tile staged in LDS, coalesced writeback ----
  __syncthreads();
  unsigned short* ct = lds;               // 128x128 bf16 = 32 KB
  #pragma unroll
  for (int mi = 0; mi < 4; mi++){
    #pragma unroll
    for (int ni = 0; ni < 4; ni++){
      int ncol = wn*64 + ni*16 + lr;
      float bn = bias[n0 + ncol];
      #pragma unroll
      for (int r = 0; r < 4; r++){
        int mrow = wm*64 + mi*16 + lg*4 + r;
        float v = acc[mi][ni][r] + bn;
        unsigned short o;
        if (MODE == 0) o = f2bf(expf(-v*v));
        else           o = f2bf(1.0f / (1.0f + expf(-v)));
        ct[mrow*128 + ncol] = o;
      }
    }
  }
  __syncthreads();
  #pragma unroll
  for (int i = 0; i < 8; i++){
    int e = (i*256 + tid) * 8;            // elem index in tile; lanes contiguous
    int row = e >> 7, col = e & 127;
    if (MODE == 0){
      *(uint4*)&Gout[(size_t)(m0+row)*N + n0+col] = *(const uint4*)&ct[e];
    } else {
      size_t gi = (size_t)(m0+row)*N + n0+col;
      s16x8 gt = *(const s16x8*)&ct[e];
      s16x8 rr = *(const s16x8*)&supR[gi];
      s16x8 qq = *(const s16x8*)&supI[gi];
      s16x8 ro, io, mo;
      #pragma unroll
      for (int j = 0; j < 8; j++){
        float g  = bf2f((unsigned short)gt[j]);
        float rf = bf2f((unsigned short)rr[j]) * g;
        float qf = bf2f((unsigned short)qq[j]) * g;
        ro[j] = (short)f2bf(rf);
        io[j] = (short)f2bf(qf);
        mo[j] = (short)f2bf(sqrtf(rf*rf + qf*qf + EPSF));
      }
      *(s16x8*)&supR[gi] = ro;
      *(s16x8*)&supI[gi] = io;
      *(s16x8*)&magout[gi] = mo;
    }
  }
}

// ---------------- stage-1 epilogue: normalization + superposition ----------------
template<int NR>
__device__ __forceinline__ void breduce(const float* vals, float* red,
                                        float* outp, int lane, int wid, int tid){
  #pragma unroll
  for (int j = 0; j < NR; j++){
    float x = vals[j];
    #pragma unroll
    for (int off = 32; off >= 1; off >>= 1) x += __shfl_down(x, off, 64);
    if (lane == 0) red[wid*NR + j] = x;
  }
  __syncthreads();
  if (tid < NR) outp[tid] = red[tid] + red[NR+tid] + red[2*NR+tid] + red[3*NR+tid];
  __syncthreads();
}

__global__ __launch_bounds__(256) void k2_superpose(
  const unsigned short* __restrict__ G, const float* __restrict__ phases,
  unsigned short* __restrict__ supR, unsigned short* __restrict__ supI,
  unsigned short* __restrict__ mag)
{
  __shared__ float red[36];
  __shared__ float outp[9];
  const int tid = threadIdx.x, lane = tid & 63, wid = tid >> 6;
  const int b = blockIdx.x;              // local row within chunk
  const size_t gbase = (size_t)b * N1;
  const int h0 = tid * 8;

  float av[S_SZ][8], bv[S_SZ][8], nsq[S_SZ];
  #pragma unroll
  for (int s = 0; s < S_SZ; s++){
    s16x8 va = *(const s16x8*)&G[gbase + s*4096 + h0];
    s16x8 vb = *(const s16x8*)&G[gbase + s*4096 + 2048 + h0];
    float accn = 0.f;
    #pragma unroll
    for (int i = 0; i < 8; i++){
      float a  = bf2f((unsigned short)va[i]);
      float bb = bf2f((unsigned short)vb[i]);
      av[s][i] = a; bv[s][i] = bb;
      accn += a*a + bb*bb;
    }
    nsq[s] = accn;
  }
  breduce<4>(nsq, red, outp, lane, wid, tid);

  float fac[S_SZ], cc[S_SZ], sn[S_SZ];
  #pragma unroll
  for (int s = 0; s < S_SZ; s++){
    fac[s] = sqrtf(2.25f / (outp[s] + EPSF));   // PARTIAL_NORM^2 = 2.25
    float ph = phases[s];
    cc[s] = cosf(ph); sn[s] = sinf(ph);
  }
  float re[S_SZ][8], im[S_SZ][8], mr[8];
  #pragma unroll
  for (int i = 0; i < 8; i++) mr[i] = 0.f;
  #pragma unroll
  for (int s = 0; s < S_SZ; s++)
    #pragma unroll
    for (int i = 0; i < 8; i++){
      float r = fac[s]*(av[s][i]*cc[s] - bv[s][i]*sn[s]);
      float qv = fac[s]*(av[s][i]*sn[s] + bv[s][i]*cc[s]);
      re[s][i] = r; im[s][i] = qv; mr[i] += r;
    }
  #pragma unroll
  for (int i = 0; i < 8; i++) mr[i] *= 0.25f;

  float pv[9];
  { float t = 0.f;
    #pragma unroll
    for (int i = 0; i < 8; i++) t += mr[i]*mr[i];
    pv[0] = t; }
  #pragma unroll
  for (int s = 0; s < S_SZ; s++){
    float t1 = 0.f, t2 = 0.f;
    #pragma unroll
    for (int i = 0; i < 8; i++){ t1 += re[s][i]*re[s][i]; t2 += re[s][i]*mr[i]; }
    pv[1+s] = t1; pv[5+s] = t2;
  }
  breduce<9>(pv, red, outp, lane, wid, tid);

  float mean_norm = sqrtf(outp[0]) + EPSF;
  float wv[S_SZ]; float mx = -1e30f;
  #pragma unroll
  for (int s = 0; s < S_SZ; s++){
    float wn = sqrtf(outp[1+s]) + EPSF;
    float csim = outp[5+s] / (wn * mean_norm);
    wv[s] = csim; mx = fmaxf(mx, csim);
  }
  float se = 0.f;
  #pragma unroll
  for (int s = 0; s < S_SZ; s++){ wv[s] = expf(wv[s]-mx); se += wv[s]; }
  float invse = 1.f / se;
  #pragma unroll
  for (int s = 0; s < S_SZ; s++) wv[s] *= invse;

  s16x8 ro, io, mo;
  #pragma unroll
  for (int i = 0; i < 8; i++){
    float sr = 0.f, si = 0.f;
    #pragma unroll
    for (int s = 0; s < S_SZ; s++){ sr += wv[s]*re[s][i]; si += wv[s]*im[s][i]; }
    ro[i] = (short)f2bf(sr); io[i] = (short)f2bf(si);
    mo[i] = (short)f2bf(sqrtf(sr*sr + si*si + EPSF));
  }
  size_t ob = (size_t)b*H_SZ + h0;
  *(s16x8*)&supR[ob] = ro;
  *(s16x8*)&supI[ob] = io;
  *(s16x8*)&mag[ob]  = mo;
}

// ---------------- top-64 + sparse output ----------------
__global__ __launch_bounds__(256) void k4_topk(
  const unsigned short* __restrict__ supR, const unsigned short* __restrict__ supI,
  const unsigned short* __restrict__ WcTb, const float* __restrict__ bcv,
  float* __restrict__ outg)
{
  __shared__ float msq[H_SZ];
  __shared__ int   redi[4];
  __shared__ int   sel_idx[64];
  __shared__ float sel_p[64];
  __shared__ int   cnt;
  __shared__ float ssum_sh;
  const int tid = threadIdx.x, lane = tid & 63, wid = tid >> 6;
  const int b = blockIdx.x;
  const size_t base = (size_t)b * H_SZ;

  if (tid < 64){ sel_p[tid] = 0.f; sel_idx[tid] = 0; }
  if (tid == 0) cnt = 0;

  float v[8]; unsigned int u[8];
  {
    s16x8 r = *(const s16x8*)&supR[base + tid*8];
    s16x8 qv = *(const s16x8*)&supI[base + tid*8];
    #pragma unroll
    for (int i = 0; i < 8; i++){
      float rf = bf2f((unsigned short)r[i]);
      float qf = bf2f((unsigned short)qv[i]);
      v[i] = rf*rf + qf*qf;
    }
  }
  #pragma unroll
  for (int i = 0; i < 8; i++){ msq[tid*8+i] = v[i]; u[i] = __float_as_uint(v[i]); }
  __syncthreads();

  unsigned int lo = 0u, hi = 0xFFFFFFFFu;
  for (int it = 0; it < 32; ++it){
    unsigned int mid = (unsigned int)(((unsigned long long)lo + (unsigned long long)hi + 1ull) >> 1);
    int c = 0;
    #pragma unroll
    for (int i = 0; i < 8; i++) c += (u[i] >= mid) ? 1 : 0;
    #pragma unroll
    for (int off = 32; off >= 1; off >>= 1) c += __shfl_down(c, off, 64);
    if (lane == 0) redi[wid] = c;
    __syncthreads();
    int total = redi[0]+redi[1]+redi[2]+redi[3];
    __syncthreads();
    if (total >= 64) lo = mid; else hi = mid - 1u;
  }
  const unsigned int V = lo;

  int cg = 0;
  #pragma unroll
  for (int i = 0; i < 8; i++) cg += (u[i] > V) ? 1 : 0;
  #pragma unroll
  for (int off = 32; off >= 1; off >>= 1) cg += __shfl_down(cg, off, 64);
  if (lane == 0) redi[wid] = cg;
  __syncthreads();
  const int ng = redi[0]+redi[1]+redi[2]+redi[3];
  const int kfill = 64 - ng;

  #pragma unroll
  for (int i = 0; i < 8; i++){
    if (u[i] > V){
      int ppos = atomicAdd(&cnt, 1);
      if (ppos < 64){ sel_idx[ppos] = tid*8 + i; sel_p[ppos] = v[i]; }
    }
  }
  __syncthreads();
  if (wid == 0){
    int taken = 0;
    for (int b2 = 0; b2 < H_SZ; b2 += 64){
      float val = msq[b2 + lane];
      bool eq = (__float_as_uint(val) == V);
      unsigned long long mk = __ballot(eq);
      int pre = __popcll(mk & ((1ull << lane) - 1ull));
      int dst = ng + taken + pre;
      if (eq && dst < 64){
        sel_idx[dst] = b2 + lane;
        sel_p [dst] = val;
      }
      taken += __popcll(mk);
      if (taken >= kfill) break;
    }
  }
  __syncthreads();
  if (wid == 0){
    float xx = sel_p[lane];
    #pragma unroll
    for (int off = 32; off >= 1; off >>= 1) xx += __shfl_down(xx, off, 64);
    if (lane == 0) ssum_sh = xx;
  }
  __syncthreads();
  const float invden = 1.f / (ssum_sh + EPSF);
  if (tid < 64) sel_p[tid] *= invden;
  __syncthreads();

  for (int c = tid; c < C_SZ; c += 256){
    float acc = bcv[c];
    #pragma unroll 8
    for (int k = 0; k < 64; k++) acc += sel_p[k] * bf2f(WcTb[(size_t)sel_idx[k]*C_SZ + c]);
    outg[(size_t)b*C_SZ + c] = acc;
  }
}

// ---------------- launch ----------------
extern "C" void kernel_launch(void* const* d_in, const int* in_sizes, int n_in,
                              void* d_out, int out_size, void* d_ws, size_t ws_size,
                              hipStream_t stream){
  (void)in_sizes; (void)n_in; (void)out_size;
  const float* x      = (const float*)d_in[0];
  const float* Wnet   = (const float*)d_in[1];
  const float* bnet   = (const float*)d_in[2];
  const float* phases = (const float*)d_in[3];
  const float* Wg     = (const float*)d_in[4];
  const float* bg     = (const float*)d_in[5];
  const float* Wc     = (const float*)d_in[6];
  const float* bc     = (const float*)d_in[7];
  float* out = (float*)d_out;

  char* p = (char*)d_ws;
  const size_t MB = 1024ull*1024ull;
  // phase A: xb (0..16MB) + Wnetb (16..48MB)
  // phase B: Wgb (0..8MB) + WcTb bf16 (8..12MB)   [xb region, dead by then]
  unsigned short* xb    = (unsigned short*)(p + 0);
  unsigned short* Wnetb = (unsigned short*)(p + 16*MB);
  unsigned short* Wgb   = (unsigned short*)(p + 0);
  unsigned short* WcTb  = (unsigned short*)(p + 8*MB);
  unsigned short* supR  = (unsigned short*)(p + 48*MB);
  unsigned short* supI  = (unsigned short*)(p + 80*MB);
  unsigned short* mag   = (unsigned short*)(p + 112*MB);
  unsigned short* G     = (unsigned short*)(p + 144*MB);

  size_t avail = (ws_size > 144*MB) ? (ws_size - 144*MB) : 0;
  long rows_cap = (long)(avail / ((size_t)N1 * 2));
  int chunk = (int)((rows_cap / BM) * BM);
  if (chunk > B_SZ) chunk = B_SZ;
  if (chunk < BM)   chunk = BM;

  cvt_bf16<<<(B_SZ*D_SZ/4 + 255)/256, 256, 0, stream>>>(x, xb, B_SZ*D_SZ/4);
  cvt_bf16<<<(N1*D_SZ/4 + 255)/256, 256, 0, stream>>>(Wnet, Wnetb, N1*D_SZ/4);

  for (int b0 = 0; b0 < B_SZ; b0 += chunk){
    int rows = (B_SZ - b0 < chunk) ? (B_SZ - b0) : chunk;
    gemm_bt<0><<<dim3(N1/BN, rows/BM), 256, 0, stream>>>(
        xb + (size_t)b0*D_SZ, Wnetb, rows, N1, D_SZ, bnet, G, nullptr, nullptr, nullptr);
    k2_superpose<<<rows, 256, 0, stream>>>(
        G, phases, supR + (size_t)b0*H_SZ, supI + (size_t)b0*H_SZ, mag + (size_t)b0*H_SZ);
  }

  // phase B
  cvt_bf16<<<(H_SZ*H_SZ/4 + 255)/256, 256, 0, stream>>>(Wg, Wgb, H_SZ*H_SZ/4);
  transpose_wc<<<(H_SZ*C_SZ + 255)/256, 256, 0, stream>>>(Wc, WcTb);

  gemm_bt<1><<<dim3(H_SZ/BN, B_SZ/BM), 256, 0, stream>>>(
      mag, Wgb, B_SZ, H_SZ, H_SZ, bg, nullptr, supR, supI, mag);
  gemm_bt<1><<<dim3(H_SZ/BN, B_SZ/BM), 256, 0, stream>>>(
      mag, Wgb, B_SZ, H_SZ, H_SZ, bg, nullptr, supR, supI, mag);

  k4_topk<<<B_SZ, 256, 0, stream>>>(supR, supI, WcTb, bc, out);
}

// Round 4
// 1032.934 us; speedup vs baseline: 2.2413x; 1.1398x over previous
//
#include <hip/hip_runtime.h>
#include <hip/hip_bf16.h>
#include <cstdint>
#include <cstddef>

#define B_SZ 8192
#define D_SZ 1024
#define H_SZ 2048
#define S_SZ 4
#define C_SZ 1000
#define N1   16384            // S*2H
#define EPSF 1e-8f

typedef __attribute__((ext_vector_type(4))) float f32x4;
typedef __attribute__((ext_vector_type(8))) short s16x8;

typedef __attribute__((address_space(3))) void lds_void;
typedef const __attribute__((address_space(1))) void glb_void;

static __device__ __forceinline__ void gload16(const void* g, void* l){
  __builtin_amdgcn_global_load_lds((glb_void*)g, (lds_void*)l, 16, 0, 0);
}

static __device__ __forceinline__ float bf2f(unsigned short u){
  union { unsigned int i; float f; } c; c.i = ((unsigned int)u) << 16; return c.f;
}
static __device__ __forceinline__ unsigned short f2bf(float f){
  union { float f; unsigned int i; } c; c.f = f;
  unsigned int x = c.i;
  return (unsigned short)((x + 0x7FFFu + ((x >> 16) & 1u)) >> 16);
}

// ---------------- conversions ----------------
__global__ __launch_bounds__(256) void cvt_bf16(const float* __restrict__ src,
                                                unsigned short* __restrict__ dst, int n4){
  int i = blockIdx.x * 256 + threadIdx.x;
  if (i >= n4) return;
  float4 v = ((const float4*)src)[i];
  ushort4 o; o.x = f2bf(v.x); o.y = f2bf(v.y); o.z = f2bf(v.z); o.w = f2bf(v.w);
  ((ushort4*)dst)[i] = o;
}

__global__ __launch_bounds__(256) void transpose_wc(const float* __restrict__ Wc,
                                                    unsigned short* __restrict__ WcTb){
  int idx = blockIdx.x * 256 + threadIdx.x;
  if (idx >= H_SZ * C_SZ) return;
  int h = idx / C_SZ, c = idx - h * C_SZ;
  WcTb[idx] = f2bf(Wc[(size_t)c * H_SZ + h]);   // WcTb: H x C bf16
}

// ---------------- MFMA GEMM: C = epilogue(A(MxK) * B(NxK)^T) ----------------
// MODE 0: Gaussian: G = bf16(exp(-(acc+bnet[n])^2))
// MODE 1: gate=sigmoid(acc+bg[n]); supR*=gate; supI*=gate; mag=sqrt(r^2+i^2+eps)
// Structure: 128x128 tile, BK=64, double-buffered LDS (T3-min 2-phase),
// T2 swizzle via pre-swizzled global source + XOR'd ds_read (rule #21).
#define BM 128
#define BN 128
#define BK 64
#define TILE_ES (BM*BK)        // elems per matrix tile (8192 = 16KB bf16)

template<int MODE>
__global__ __launch_bounds__(256) void gemm_bt(
    const unsigned short* __restrict__ A,   // M x K bf16
    const unsigned short* __restrict__ Bm,  // N x K bf16
    int M, int N, int K,
    const float* __restrict__ bias,         // length N
    unsigned short* __restrict__ Gout,      // MODE 0 out (M x N bf16)
    unsigned short* __restrict__ supR,      // MODE 1 inout bf16
    unsigned short* __restrict__ supI,      // MODE 1 inout bf16
    unsigned short* __restrict__ magout)    // MODE 1 out bf16
{
  __shared__ __align__(16) unsigned short lds[2*2*TILE_ES];   // 64 KB: [buf][A|B]
  const int tid = threadIdx.x;
  const int lane = tid & 63;
  const int w = tid >> 6;
  const int wm = w >> 1, wn = w & 1;
  const int lr = lane & 15, lg = lane >> 4;
  const int srow = lane >> 3;                        // 0..7 within 8-row seg
  const int scol = ((lane & 7) ^ (lane >> 3)) * 8;   // pre-swizzled source chunk

  // bijective XCD swizzle (m204)
  const int gx = gridDim.x;
  const int nwg = gx * gridDim.y;
  const int bid = blockIdx.y * gx + blockIdx.x;
  const int q = nwg >> 3, rmd = nwg & 7, xcd = bid & 7, lid = bid >> 3;
  const int swz = (xcd < rmd ? xcd*(q+1) : rmd*(q+1) + (xcd-rmd)*q) + lid;
  const int m0 = (swz / gx) * BM;
  const int n0 = (swz % gx) * BN;

  const unsigned short* gaBase = A  + (size_t)m0*K + (size_t)(srow)*K + scol;
  const unsigned short* gbBase = Bm + (size_t)n0*K + (size_t)(srow)*K + scol;

  f32x4 acc[4][4];
  #pragma unroll
  for (int i = 0; i < 4; i++)
    #pragma unroll
    for (int j = 0; j < 4; j++){ f32x4 z = {0.f,0.f,0.f,0.f}; acc[i][j] = z; }

  const int nkt = K / BK;

  // ---- STAGE macro: issue 8 gload16 for tile kt into buffer bi ----
  #define STAGE(bi, kt) do {                                                   \
    unsigned short* la_ = lds + (bi)*2*TILE_ES;                                \
    unsigned short* lb_ = la_ + TILE_ES;                                       \
    const size_t ko_ = (size_t)(kt)*BK;                                        \
    _Pragma("unroll")                                                          \
    for (int i_ = 0; i_ < 4; i_++){                                            \
      int seg_ = i_*4 + w;                                                     \
      gload16(gaBase + (size_t)(seg_*8)*K + ko_, &la_[seg_*512]);              \
      gload16(gbBase + (size_t)(seg_*8)*K + ko_, &lb_[seg_*512]);              \
    }                                                                          \
  } while(0)

  // prologue
  STAGE(0, 0);
  asm volatile("s_waitcnt vmcnt(0)" ::: "memory");
  __builtin_amdgcn_s_barrier();

  int cur = 0;
  for (int kt = 0; kt < nkt; ++kt){
    if (kt + 1 < nkt) STAGE(cur ^ 1, kt + 1);      // loads fly under compute
    const unsigned short* la = lds + cur*2*TILE_ES;
    const unsigned short* lb = la + TILE_ES;
    #pragma unroll
    for (int kk = 0; kk < 2; ++kk){
      s16x8 af[4], bfr[4];
      #pragma unroll
      for (int mi = 0; mi < 4; mi++){
        int row = wm*64 + mi*16 + lr;
        int ch  = (kk*4 + lg) ^ (lr & 7);          // XOR-swizzled chunk
        af[mi] = *(const s16x8*)&la[row*BK + ch*8];
      }
      #pragma unroll
      for (int ni = 0; ni < 4; ni++){
        int row = wn*64 + ni*16 + lr;
        int ch  = (kk*4 + lg) ^ (lr & 7);
        bfr[ni] = *(const s16x8*)&lb[row*BK + ch*8];
      }
      #pragma unroll
      for (int mi = 0; mi < 4; mi++)
        #pragma unroll
        for (int ni = 0; ni < 4; ni++)
          acc[mi][ni] = __builtin_amdgcn_mfma_f32_16x16x32_bf16(af[mi], bfr[ni], acc[mi][ni], 0, 0, 0);
    }
    asm volatile("s_waitcnt vmcnt(0)" ::: "memory"); // next-tile loads landed
    __builtin_amdgcn_s_barrier();
    cur ^= 1;
  }
  #undef STAGE

  // ---- epilogue: bf16 result tile staged in LDS (buf0), coalesced writeback ----
  unsigned short* ct = lds;               // 128x128 bf16 = 32 KB
  #pragma unroll
  for (int mi = 0; mi < 4; mi++){
    #pragma unroll
    for (int ni = 0; ni < 4; ni++){
      int ncol = wn*64 + ni*16 + lr;
      float bn = bias[n0 + ncol];
      #pragma unroll
      for (int r = 0; r < 4; r++){
        int mrow = wm*64 + mi*16 + lg*4 + r;
        float v = acc[mi][ni][r] + bn;
        unsigned short o;
        if (MODE == 0) o = f2bf(expf(-v*v));
        else           o = f2bf(1.0f / (1.0f + expf(-v)));
        ct[mrow*128 + ncol] = o;
      }
    }
  }
  __syncthreads();
  #pragma unroll
  for (int i = 0; i < 8; i++){
    int e = (i*256 + tid) * 8;            // elem index in tile; lanes contiguous
    int row = e >> 7, col = e & 127;
    if (MODE == 0){
      *(uint4*)&Gout[(size_t)(m0+row)*N + n0+col] = *(const uint4*)&ct[e];
    } else {
      size_t gi = (size_t)(m0+row)*N + n0+col;
      s16x8 gt = *(const s16x8*)&ct[e];
      s16x8 rr = *(const s16x8*)&supR[gi];
      s16x8 qq = *(const s16x8*)&supI[gi];
      s16x8 ro, io, mo;
      #pragma unroll
      for (int j = 0; j < 8; j++){
        float g  = bf2f((unsigned short)gt[j]);
        float rf = bf2f((unsigned short)rr[j]) * g;
        float qf = bf2f((unsigned short)qq[j]) * g;
        ro[j] = (short)f2bf(rf);
        io[j] = (short)f2bf(qf);
        mo[j] = (short)f2bf(sqrtf(rf*rf + qf*qf + EPSF));
      }
      *(s16x8*)&supR[gi] = ro;
      *(s16x8*)&supI[gi] = io;
      *(s16x8*)&magout[gi] = mo;
    }
  }
}

// ---------------- stage-1 epilogue: normalization + superposition ----------------
template<int NR>
__device__ __forceinline__ void breduce(const float* vals, float* red,
                                        float* outp, int lane, int wid, int tid){
  #pragma unroll
  for (int j = 0; j < NR; j++){
    float x = vals[j];
    #pragma unroll
    for (int off = 32; off >= 1; off >>= 1) x += __shfl_down(x, off, 64);
    if (lane == 0) red[wid*NR + j] = x;
  }
  __syncthreads();
  if (tid < NR) outp[tid] = red[tid] + red[NR+tid] + red[2*NR+tid] + red[3*NR+tid];
  __syncthreads();
}

__global__ __launch_bounds__(256) void k2_superpose(
  const unsigned short* __restrict__ G, const float* __restrict__ phases,
  unsigned short* __restrict__ supR, unsigned short* __restrict__ supI,
  unsigned short* __restrict__ mag)
{
  __shared__ float red[36];
  __shared__ float outp[9];
  const int tid = threadIdx.x, lane = tid & 63, wid = tid >> 6;
  const int b = blockIdx.x;              // local row within chunk
  const size_t gbase = (size_t)b * N1;
  const int h0 = tid * 8;

  float av[S_SZ][8], bv[S_SZ][8], nsq[S_SZ];
  #pragma unroll
  for (int s = 0; s < S_SZ; s++){
    s16x8 va = *(const s16x8*)&G[gbase + s*4096 + h0];
    s16x8 vb = *(const s16x8*)&G[gbase + s*4096 + 2048 + h0];
    float accn = 0.f;
    #pragma unroll
    for (int i = 0; i < 8; i++){
      float a  = bf2f((unsigned short)va[i]);
      float bb = bf2f((unsigned short)vb[i]);
      av[s][i] = a; bv[s][i] = bb;
      accn += a*a + bb*bb;
    }
    nsq[s] = accn;
  }
  breduce<4>(nsq, red, outp, lane, wid, tid);

  float fac[S_SZ], cc[S_SZ], sn[S_SZ];
  #pragma unroll
  for (int s = 0; s < S_SZ; s++){
    fac[s] = sqrtf(2.25f / (outp[s] + EPSF));   // PARTIAL_NORM^2 = 2.25
    float ph = phases[s];
    cc[s] = cosf(ph); sn[s] = sinf(ph);
  }
  float re[S_SZ][8], im[S_SZ][8], mr[8];
  #pragma unroll
  for (int i = 0; i < 8; i++) mr[i] = 0.f;
  #pragma unroll
  for (int s = 0; s < S_SZ; s++)
    #pragma unroll
    for (int i = 0; i < 8; i++){
      float r = fac[s]*(av[s][i]*cc[s] - bv[s][i]*sn[s]);
      float qv = fac[s]*(av[s][i]*sn[s] + bv[s][i]*cc[s]);
      re[s][i] = r; im[s][i] = qv; mr[i] += r;
    }
  #pragma unroll
  for (int i = 0; i < 8; i++) mr[i] *= 0.25f;

  float pv[9];
  { float t = 0.f;
    #pragma unroll
    for (int i = 0; i < 8; i++) t += mr[i]*mr[i];
    pv[0] = t; }
  #pragma unroll
  for (int s = 0; s < S_SZ; s++){
    float t1 = 0.f, t2 = 0.f;
    #pragma unroll
    for (int i = 0; i < 8; i++){ t1 += re[s][i]*re[s][i]; t2 += re[s][i]*mr[i]; }
    pv[1+s] = t1; pv[5+s] = t2;
  }
  breduce<9>(pv, red, outp, lane, wid, tid);

  float mean_norm = sqrtf(outp[0]) + EPSF;
  float wv[S_SZ]; float mx = -1e30f;
  #pragma unroll
  for (int s = 0; s < S_SZ; s++){
    float wn = sqrtf(outp[1+s]) + EPSF;
    float csim = outp[5+s] / (wn * mean_norm);
    wv[s] = csim; mx = fmaxf(mx, csim);
  }
  float se = 0.f;
  #pragma unroll
  for (int s = 0; s < S_SZ; s++){ wv[s] = expf(wv[s]-mx); se += wv[s]; }
  float invse = 1.f / se;
  #pragma unroll
  for (int s = 0; s < S_SZ; s++) wv[s] *= invse;

  s16x8 ro, io, mo;
  #pragma unroll
  for (int i = 0; i < 8; i++){
    float sr = 0.f, si = 0.f;
    #pragma unroll
    for (int s = 0; s < S_SZ; s++){ sr += wv[s]*re[s][i]; si += wv[s]*im[s][i]; }
    ro[i] = (short)f2bf(sr); io[i] = (short)f2bf(si);
    mo[i] = (short)f2bf(sqrtf(sr*sr + si*si + EPSF));
  }
  size_t ob = (size_t)b*H_SZ + h0;
  *(s16x8*)&supR[ob] = ro;
  *(s16x8*)&supI[ob] = io;
  *(s16x8*)&mag[ob]  = mo;
}

// ---------------- top-64 + sparse output ----------------
__global__ __launch_bounds__(256) void k4_topk(
  const unsigned short* __restrict__ supR, const unsigned short* __restrict__ supI,
  const unsigned short* __restrict__ WcTb, const float* __restrict__ bcv,
  float* __restrict__ outg)
{
  __shared__ float msq[H_SZ];
  __shared__ int   redi[4];
  __shared__ int   sel_idx[64];
  __shared__ float sel_p[64];
  __shared__ int   cnt;
  __shared__ float ssum_sh;
  const int tid = threadIdx.x, lane = tid & 63, wid = tid >> 6;
  const int b = blockIdx.x;
  const size_t base = (size_t)b * H_SZ;

  if (tid < 64){ sel_p[tid] = 0.f; sel_idx[tid] = 0; }
  if (tid == 0) cnt = 0;

  float v[8]; unsigned int u[8];
  {
    s16x8 r = *(const s16x8*)&supR[base + tid*8];
    s16x8 qv = *(const s16x8*)&supI[base + tid*8];
    #pragma unroll
    for (int i = 0; i < 8; i++){
      float rf = bf2f((unsigned short)r[i]);
      float qf = bf2f((unsigned short)qv[i]);
      v[i] = rf*rf + qf*qf;
    }
  }
  #pragma unroll
  for (int i = 0; i < 8; i++){ msq[tid*8+i] = v[i]; u[i] = __float_as_uint(v[i]); }
  __syncthreads();

  unsigned int lo = 0u, hi = 0xFFFFFFFFu;
  for (int it = 0; it < 32; ++it){
    unsigned int mid = (unsigned int)(((unsigned long long)lo + (unsigned long long)hi + 1ull) >> 1);
    int c = 0;
    #pragma unroll
    for (int i = 0; i < 8; i++) c += (u[i] >= mid) ? 1 : 0;
    #pragma unroll
    for (int off = 32; off >= 1; off >>= 1) c += __shfl_down(c, off, 64);
    if (lane == 0) redi[wid] = c;
    __syncthreads();
    int total = redi[0]+redi[1]+redi[2]+redi[3];
    __syncthreads();
    if (total >= 64) lo = mid; else hi = mid - 1u;
  }
  const unsigned int V = lo;

  int cg = 0;
  #pragma unroll
  for (int i = 0; i < 8; i++) cg += (u[i] > V) ? 1 : 0;
  #pragma unroll
  for (int off = 32; off >= 1; off >>= 1) cg += __shfl_down(cg, off, 64);
  if (lane == 0) redi[wid] = cg;
  __syncthreads();
  const int ng = redi[0]+redi[1]+redi[2]+redi[3];
  const int kfill = 64 - ng;

  #pragma unroll
  for (int i = 0; i < 8; i++){
    if (u[i] > V){
      int ppos = atomicAdd(&cnt, 1);
      if (ppos < 64){ sel_idx[ppos] = tid*8 + i; sel_p[ppos] = v[i]; }
    }
  }
  __syncthreads();
  if (wid == 0){
    int taken = 0;
    for (int b2 = 0; b2 < H_SZ; b2 += 64){
      float val = msq[b2 + lane];
      bool eq = (__float_as_uint(val) == V);
      unsigned long long mk = __ballot(eq);
      int pre = __popcll(mk & ((1ull << lane) - 1ull));
      int dst = ng + taken + pre;
      if (eq && dst < 64){
        sel_idx[dst] = b2 + lane;
        sel_p [dst] = val;
      }
      taken += __popcll(mk);
      if (taken >= kfill) break;
    }
  }
  __syncthreads();
  if (wid == 0){
    float xx = sel_p[lane];
    #pragma unroll
    for (int off = 32; off >= 1; off >>= 1) xx += __shfl_down(xx, off, 64);
    if (lane == 0) ssum_sh = xx;
  }
  __syncthreads();
  const float invden = 1.f / (ssum_sh + EPSF);
  if (tid < 64) sel_p[tid] *= invden;
  __syncthreads();

  for (int c = tid; c < C_SZ; c += 256){
    float acc = bcv[c];
    #pragma unroll 8
    for (int k = 0; k < 64; k++) acc += sel_p[k] * bf2f(WcTb[(size_t)sel_idx[k]*C_SZ + c]);
    outg[(size_t)b*C_SZ + c] = acc;
  }
}

// ---------------- launch ----------------
extern "C" void kernel_launch(void* const* d_in, const int* in_sizes, int n_in,
                              void* d_out, int out_size, void* d_ws, size_t ws_size,
                              hipStream_t stream){
  (void)in_sizes; (void)n_in; (void)out_size;
  const float* x      = (const float*)d_in[0];
  const float* Wnet   = (const float*)d_in[1];
  const float* bnet   = (const float*)d_in[2];
  const float* phases = (const float*)d_in[3];
  const float* Wg     = (const float*)d_in[4];
  const float* bg     = (const float*)d_in[5];
  const float* Wc     = (const float*)d_in[6];
  const float* bc     = (const float*)d_in[7];
  float* out = (float*)d_out;

  char* p = (char*)d_ws;
  const size_t MB = 1024ull*1024ull;
  // phase A: xb (0..16MB) + Wnetb (16..48MB)
  // phase B: Wgb (0..8MB) + WcTb bf16 (8..12MB)   [xb region, dead by then]
  unsigned short* xb    = (unsigned short*)(p + 0);
  unsigned short* Wnetb = (unsigned short*)(p + 16*MB);
  unsigned short* Wgb   = (unsigned short*)(p + 0);
  unsigned short* WcTb  = (unsigned short*)(p + 8*MB);
  unsigned short* supR  = (unsigned short*)(p + 48*MB);
  unsigned short* supI  = (unsigned short*)(p + 80*MB);
  unsigned short* mag   = (unsigned short*)(p + 112*MB);
  unsigned short* G     = (unsigned short*)(p + 144*MB);

  size_t avail = (ws_size > 144*MB) ? (ws_size - 144*MB) : 0;
  long rows_cap = (long)(avail / ((size_t)N1 * 2));
  int chunk = (int)((rows_cap / BM) * BM);
  if (chunk > B_SZ) chunk = B_SZ;
  if (chunk < BM)   chunk = BM;

  cvt_bf16<<<(B_SZ*D_SZ/4 + 255)/256, 256, 0, stream>>>(x, xb, B_SZ*D_SZ/4);
  cvt_bf16<<<(N1*D_SZ/4 + 255)/256, 256, 0, stream>>>(Wnet, Wnetb, N1*D_SZ/4);

  for (int b0 = 0; b0 < B_SZ; b0 += chunk){
    int rows = (B_SZ - b0 < chunk) ? (B_SZ - b0) : chunk;
    gemm_bt<0><<<dim3(N1/BN, rows/BM), 256, 0, stream>>>(
        xb + (size_t)b0*D_SZ, Wnetb, rows, N1, D_SZ, bnet, G, nullptr, nullptr, nullptr);
    k2_superpose<<<rows, 256, 0, stream>>>(
        G, phases, supR + (size_t)b0*H_SZ, supI + (size_t)b0*H_SZ, mag + (size_t)b0*H_SZ);
  }

  // phase B
  cvt_bf16<<<(H_SZ*H_SZ/4 + 255)/256, 256, 0, stream>>>(Wg, Wgb, H_SZ*H_SZ/4);
  transpose_wc<<<(H_SZ*C_SZ + 255)/256, 256, 0, stream>>>(Wc, WcTb);

  gemm_bt<1><<<dim3(H_SZ/BN, B_SZ/BM), 256, 0, stream>>>(
      mag, Wgb, B_SZ, H_SZ, H_SZ, bg, nullptr, supR, supI, mag);
  gemm_bt<1><<<dim3(H_SZ/BN, B_SZ/BM), 256, 0, stream>>>(
      mag, Wgb, B_SZ, H_SZ, H_SZ, bg, nullptr, supR, supI, mag);

  k4_topk<<<B_SZ, 256, 0, stream>>>(supR, supI, WcTb, bc, out);
}

// Round 5
// 987.007 us; speedup vs baseline: 2.3455x; 1.0465x over previous
//
#include <hip/hip_runtime.h>
#include <hip/hip_bf16.h>
#include <cstdint>
#include <cstddef>

#define B_SZ 8192
#define D_SZ 1024
#define H_SZ 2048
#define S_SZ 4
#define C_SZ 1000
#define N1   16384            // S*2H
#define EPSF 1e-8f

typedef __attribute__((ext_vector_type(4))) float f32x4;
typedef __attribute__((ext_vector_type(8))) short s16x8;

typedef __attribute__((address_space(3))) void lds_void;
typedef const __attribute__((address_space(1))) void glb_void;

static __device__ __forceinline__ void gload16(const void* g, void* l){
  __builtin_amdgcn_global_load_lds((glb_void*)g, (lds_void*)l, 16, 0, 0);
}

static __device__ __forceinline__ float bf2f(unsigned short u){
  union { unsigned int i; float f; } c; c.i = ((unsigned int)u) << 16; return c.f;
}
static __device__ __forceinline__ unsigned short f2bf(float f){
  union { float f; unsigned int i; } c; c.f = f;
  unsigned int x = c.i;
  return (unsigned short)((x + 0x7FFFu + ((x >> 16) & 1u)) >> 16);
}

// ---------------- conversions ----------------
__global__ __launch_bounds__(256) void cvt_bf16(const float* __restrict__ src,
                                                unsigned short* __restrict__ dst, int n4){
  int i = blockIdx.x * 256 + threadIdx.x;
  if (i >= n4) return;
  float4 v = ((const float4*)src)[i];
  ushort4 o; o.x = f2bf(v.x); o.y = f2bf(v.y); o.z = f2bf(v.z); o.w = f2bf(v.w);
  ((ushort4*)dst)[i] = o;
}

__global__ __launch_bounds__(256) void transpose_wc(const float* __restrict__ Wc,
                                                    unsigned short* __restrict__ WcTb){
  int idx = blockIdx.x * 256 + threadIdx.x;
  if (idx >= H_SZ * C_SZ) return;
  int h = idx / C_SZ, c = idx - h * C_SZ;
  WcTb[idx] = f2bf(Wc[(size_t)c * H_SZ + h]);   // WcTb: H x C bf16
}

// ---------------- 256x256 8-phase MFMA GEMM: C = epi(A(MxK) * B(NxK)^T) ----------------
// MODE 0: Gaussian: G = bf16(exp(-(acc+bias[n])^2))
// MODE 1: gate=sigmoid(acc+bias[n]); supR*=gate; supI*=gate; mag=sqrt(r^2+i^2+eps)
// 8 waves (2M x 4N), BK=64, LDS 128KB = 2 K-tile bufs x (A 32KB | B 32KB).
// T2 swizzle: pre-swizzled global src + XOR'd ds_read. T3/T4: counted vmcnt(4)
// once per K-tile. T5: setprio around MFMA clusters.

template<int MODE>
__global__ __launch_bounds__(512, 2) void gemm8(
    const unsigned short* __restrict__ A,   // M x K bf16
    const unsigned short* __restrict__ Bm,  // N x K bf16
    int M, int N, int K,
    const float* __restrict__ bias,         // length N
    unsigned short* __restrict__ Gout,      // MODE 0 out (M x N bf16)
    unsigned short* __restrict__ supR,      // MODE 1 inout bf16
    unsigned short* __restrict__ supI,      // MODE 1 inout bf16
    unsigned short* __restrict__ magout)    // MODE 1 out bf16
{
  __shared__ __align__(16) unsigned short lds[65536];   // 128 KB
  const int tid = threadIdx.x;
  const int lane = tid & 63;
  const int w = tid >> 6;                 // wave 0..7
  const int wm = w >> 2, wn = w & 3;      // 2 x 4
  const int lr = lane & 15, lg = lane >> 4;
  const int rowq = lane >> 3;             // 0..7
  const int sc8 = ((lane & 7) ^ rowq) * 8;  // pre-swizzled source chunk (elems)
  const int ch0 = (0*4 + lg) ^ (lr & 7);  // kk=0 read chunk
  const int ch1 = (1*4 + lg) ^ (lr & 7);  // kk=1 read chunk

  // bijective XCD swizzle (m204)
  const int gx = gridDim.x;
  const int nwg = gx * gridDim.y;
  const int bid = blockIdx.y * gx + blockIdx.x;
  const int q = nwg >> 3, rmd = nwg & 7, xcd = bid & 7, lid = bid >> 3;
  const int swz = (xcd < rmd ? xcd*(q+1) : rmd*(q+1) + (xcd-rmd)*q) + lid;
  const int m0 = (swz / gx) * 256;
  const int n0 = (swz % gx) * 256;

  const unsigned short* ga = A  + (size_t)m0*K;
  const unsigned short* gb = Bm + (size_t)n0*K;

  f32x4 acc[8][4];
  #pragma unroll
  for (int i = 0; i < 8; i++)
    #pragma unroll
    for (int j = 0; j < 4; j++){ f32x4 z = {0.f,0.f,0.f,0.f}; acc[i][j] = z; }

  // stage one half-tile (128 rows x 64 cols) of matrix `base` for K-tile kt.
  // ldsbase = buf*32768 (+16384 for B). 2 gload16/thread, dest wave-uniform.
  auto stage_half = [&](const unsigned short* base, int half, int kt, int ldsbase){
    #pragma unroll
    for (int j = 0; j < 2; j++){
      int seg = j*8 + w;
      const unsigned short* g = base + (size_t)(half*128 + seg*8 + rowq)*K + kt*64 + sc8;
      gload16(g, &lds[ldsbase + half*8192 + seg*512]);
    }
  };

  const int nkt = K >> 6;

  // prologue: K-tile 0 fully, A-halves of K-tile 1
  stage_half(ga, 0, 0, 0);      stage_half(ga, 1, 0, 0);
  stage_half(gb, 0, 0, 16384);  stage_half(gb, 1, 0, 16384);
  stage_half(ga, 0, 1, 32768);  stage_half(ga, 1, 1, 32768);
  asm volatile("s_waitcnt vmcnt(0)" ::: "memory");
  __builtin_amdgcn_s_barrier();

  for (int t = 0; t < nkt; ++t){
    const int bo = (t & 1) << 15;         // current buf (elems)
    const int bn = 32768 - bo;            // next buf
    s16x8 a03[4][2], a47[4][2], bfr[4][2];

    // ---- ph1: read a[0..3] + all b; stage B0(t+1); MFMA Q(0,0) ----
    #pragma unroll
    for (int f = 0; f < 4; f++){
      int r = wm*128 + f*16 + lr;
      a03[f][0] = *(const s16x8*)&lds[bo + r*64 + ch0*8];
      a03[f][1] = *(const s16x8*)&lds[bo + r*64 + ch1*8];
    }
    #pragma unroll
    for (int nf = 0; nf < 4; nf++){
      int r = wn*64 + nf*16 + lr;
      bfr[nf][0] = *(const s16x8*)&lds[bo + 16384 + r*64 + ch0*8];
      bfr[nf][1] = *(const s16x8*)&lds[bo + 16384 + r*64 + ch1*8];
    }
    if (t + 1 < nkt) stage_half(gb, 0, t+1, bn + 16384);
    __builtin_amdgcn_s_barrier();
    asm volatile("s_waitcnt lgkmcnt(0)" ::: "memory");
    __builtin_amdgcn_sched_barrier(0);
    __builtin_amdgcn_s_setprio(1);
    #pragma unroll
    for (int f = 0; f < 4; f++)
      #pragma unroll
      for (int nf = 0; nf < 2; nf++){
        acc[f][nf] = __builtin_amdgcn_mfma_f32_16x16x32_bf16(a03[f][0], bfr[nf][0], acc[f][nf], 0,0,0);
        acc[f][nf] = __builtin_amdgcn_mfma_f32_16x16x32_bf16(a03[f][1], bfr[nf][1], acc[f][nf], 0,0,0);
      }
    __builtin_amdgcn_s_setprio(0);
    __builtin_amdgcn_s_barrier();

    // ---- ph2: read a[4..7]; stage B1(t+1); MFMA Q(0,1) ----
    #pragma unroll
    for (int f = 0; f < 4; f++){
      int r = wm*128 + 64 + f*16 + lr;
      a47[f][0] = *(const s16x8*)&lds[bo + r*64 + ch0*8];
      a47[f][1] = *(const s16x8*)&lds[bo + r*64 + ch1*8];
    }
    if (t + 1 < nkt) stage_half(gb, 1, t+1, bn + 16384);
    __builtin_amdgcn_s_barrier();
    asm volatile("s_waitcnt lgkmcnt(0)" ::: "memory");
    __builtin_amdgcn_sched_barrier(0);
    __builtin_amdgcn_s_setprio(1);
    #pragma unroll
    for (int f = 0; f < 4; f++)
      #pragma unroll
      for (int nf = 2; nf < 4; nf++){
        acc[f][nf] = __builtin_amdgcn_mfma_f32_16x16x32_bf16(a03[f][0], bfr[nf][0], acc[f][nf], 0,0,0);
        acc[f][nf] = __builtin_amdgcn_mfma_f32_16x16x32_bf16(a03[f][1], bfr[nf][1], acc[f][nf], 0,0,0);
      }
    __builtin_amdgcn_s_setprio(0);
    __builtin_amdgcn_s_barrier();

    // ---- ph3: stage A0(t+2) into current buf (its reads are complete); MFMA Q(1,0) ----
    if (t + 2 < nkt) stage_half(ga, 0, t+2, bo);
    __builtin_amdgcn_s_barrier();
    __builtin_amdgcn_s_setprio(1);
    #pragma unroll
    for (int f = 0; f < 4; f++)
      #pragma unroll
      for (int nf = 0; nf < 2; nf++){
        acc[4+f][nf] = __builtin_amdgcn_mfma_f32_16x16x32_bf16(a47[f][0], bfr[nf][0], acc[4+f][nf], 0,0,0);
        acc[4+f][nf] = __builtin_amdgcn_mfma_f32_16x16x32_bf16(a47[f][1], bfr[nf][1], acc[4+f][nf], 0,0,0);
      }
    __builtin_amdgcn_s_setprio(0);
    __builtin_amdgcn_s_barrier();

    // ---- ph4: stage A1(t+2); MFMA Q(1,1); counted vmcnt gate ----
    if (t + 2 < nkt) stage_half(ga, 1, t+2, bo);
    __builtin_amdgcn_s_barrier();
    __builtin_amdgcn_s_setprio(1);
    #pragma unroll
    for (int f = 0; f < 4; f++)
      #pragma unroll
      for (int nf = 2; nf < 4; nf++){
        acc[4+f][nf] = __builtin_amdgcn_mfma_f32_16x16x32_bf16(a47[f][0], bfr[nf][0], acc[4+f][nf], 0,0,0);
        acc[4+f][nf] = __builtin_amdgcn_mfma_f32_16x16x32_bf16(a47[f][1], bfr[nf][1], acc[4+f][nf], 0,0,0);
      }
    __builtin_amdgcn_s_setprio(0);
    asm volatile("s_waitcnt vmcnt(4)" ::: "memory");  // B(t+1) landed; A(t+2) in flight
    __builtin_amdgcn_s_barrier();
  }

  // ---- epilogue: full 256x256 bf16 C-tile staged in LDS, coalesced writeback ----
  asm volatile("s_waitcnt vmcnt(0)" ::: "memory");
  __builtin_amdgcn_s_barrier();
  #pragma unroll
  for (int f = 0; f < 8; f++){
    #pragma unroll
    for (int nf = 0; nf < 4; nf++){
      int ncol = wn*64 + nf*16 + lr;
      float bn = bias[n0 + ncol];
      #pragma unroll
      for (int r = 0; r < 4; r++){
        int mrow = wm*128 + f*16 + lg*4 + r;
        float v = acc[f][nf][r] + bn;
        unsigned short o;
        if (MODE == 0) o = f2bf(expf(-v*v));
        else           o = f2bf(1.0f / (1.0f + expf(-v)));
        lds[mrow*256 + ncol] = o;
      }
    }
  }
  __syncthreads();
  #pragma unroll
  for (int i = 0; i < 16; i++){
    int e = (i*512 + tid) * 8;
    int row = e >> 8, col = e & 255;
    if (MODE == 0){
      *(uint4*)&Gout[(size_t)(m0+row)*N + n0+col] = *(const uint4*)&lds[e];
    } else {
      size_t gi = (size_t)(m0+row)*N + n0+col;
      s16x8 gt = *(const s16x8*)&lds[e];
      s16x8 rr = *(const s16x8*)&supR[gi];
      s16x8 qq = *(const s16x8*)&supI[gi];
      s16x8 ro, io, mo;
      #pragma unroll
      for (int j = 0; j < 8; j++){
        float g  = bf2f((unsigned short)gt[j]);
        float rf = bf2f((unsigned short)rr[j]) * g;
        float qf = bf2f((unsigned short)qq[j]) * g;
        ro[j] = (short)f2bf(rf);
        io[j] = (short)f2bf(qf);
        mo[j] = (short)f2bf(sqrtf(rf*rf + qf*qf + EPSF));
      }
      *(s16x8*)&supR[gi] = ro;
      *(s16x8*)&supI[gi] = io;
      *(s16x8*)&magout[gi] = mo;
    }
  }
}

// ---------------- stage-1 epilogue: normalization + superposition ----------------
template<int NR>
__device__ __forceinline__ void breduce(const float* vals, float* red,
                                        float* outp, int lane, int wid, int tid){
  #pragma unroll
  for (int j = 0; j < NR; j++){
    float x = vals[j];
    #pragma unroll
    for (int off = 32; off >= 1; off >>= 1) x += __shfl_down(x, off, 64);
    if (lane == 0) red[wid*NR + j] = x;
  }
  __syncthreads();
  if (tid < NR) outp[tid] = red[tid] + red[NR+tid] + red[2*NR+tid] + red[3*NR+tid];
  __syncthreads();
}

__global__ __launch_bounds__(256) void k2_superpose(
  const unsigned short* __restrict__ G, const float* __restrict__ phases,
  unsigned short* __restrict__ supR, unsigned short* __restrict__ supI,
  unsigned short* __restrict__ mag)
{
  __shared__ float red[36];
  __shared__ float outp[9];
  const int tid = threadIdx.x, lane = tid & 63, wid = tid >> 6;
  const int b = blockIdx.x;              // local row within chunk
  const size_t gbase = (size_t)b * N1;
  const int h0 = tid * 8;

  float av[S_SZ][8], bv[S_SZ][8], nsq[S_SZ];
  #pragma unroll
  for (int s = 0; s < S_SZ; s++){
    s16x8 va = *(const s16x8*)&G[gbase + s*4096 + h0];
    s16x8 vb = *(const s16x8*)&G[gbase + s*4096 + 2048 + h0];
    float accn = 0.f;
    #pragma unroll
    for (int i = 0; i < 8; i++){
      float a  = bf2f((unsigned short)va[i]);
      float bb = bf2f((unsigned short)vb[i]);
      av[s][i] = a; bv[s][i] = bb;
      accn += a*a + bb*bb;
    }
    nsq[s] = accn;
  }
  breduce<4>(nsq, red, outp, lane, wid, tid);

  float fac[S_SZ], cc[S_SZ], sn[S_SZ];
  #pragma unroll
  for (int s = 0; s < S_SZ; s++){
    fac[s] = sqrtf(2.25f / (outp[s] + EPSF));   // PARTIAL_NORM^2 = 2.25
    float ph = phases[s];
    cc[s] = cosf(ph); sn[s] = sinf(ph);
  }
  float re[S_SZ][8], im[S_SZ][8], mr[8];
  #pragma unroll
  for (int i = 0; i < 8; i++) mr[i] = 0.f;
  #pragma unroll
  for (int s = 0; s < S_SZ; s++)
    #pragma unroll
    for (int i = 0; i < 8; i++){
      float r = fac[s]*(av[s][i]*cc[s] - bv[s][i]*sn[s]);
      float qv = fac[s]*(av[s][i]*sn[s] + bv[s][i]*cc[s]);
      re[s][i] = r; im[s][i] = qv; mr[i] += r;
    }
  #pragma unroll
  for (int i = 0; i < 8; i++) mr[i] *= 0.25f;

  float pv[9];
  { float t = 0.f;
    #pragma unroll
    for (int i = 0; i < 8; i++) t += mr[i]*mr[i];
    pv[0] = t; }
  #pragma unroll
  for (int s = 0; s < S_SZ; s++){
    float t1 = 0.f, t2 = 0.f;
    #pragma unroll
    for (int i = 0; i < 8; i++){ t1 += re[s][i]*re[s][i]; t2 += re[s][i]*mr[i]; }
    pv[1+s] = t1; pv[5+s] = t2;
  }
  breduce<9>(pv, red, outp, lane, wid, tid);

  float mean_norm = sqrtf(outp[0]) + EPSF;
  float wv[S_SZ]; float mx = -1e30f;
  #pragma unroll
  for (int s = 0; s < S_SZ; s++){
    float wn = sqrtf(outp[1+s]) + EPSF;
    float csim = outp[5+s] / (wn * mean_norm);
    wv[s] = csim; mx = fmaxf(mx, csim);
  }
  float se = 0.f;
  #pragma unroll
  for (int s = 0; s < S_SZ; s++){ wv[s] = expf(wv[s]-mx); se += wv[s]; }
  float invse = 1.f / se;
  #pragma unroll
  for (int s = 0; s < S_SZ; s++) wv[s] *= invse;

  s16x8 ro, io, mo;
  #pragma unroll
  for (int i = 0; i < 8; i++){
    float sr = 0.f, si = 0.f;
    #pragma unroll
    for (int s = 0; s < S_SZ; s++){ sr += wv[s]*re[s][i]; si += wv[s]*im[s][i]; }
    ro[i] = (short)f2bf(sr); io[i] = (short)f2bf(si);
    mo[i] = (short)f2bf(sqrtf(sr*sr + si*si + EPSF));
  }
  size_t ob = (size_t)b*H_SZ + h0;
  *(s16x8*)&supR[ob] = ro;
  *(s16x8*)&supI[ob] = io;
  *(s16x8*)&mag[ob]  = mo;
}

// ---------------- top-64 + sparse output ----------------
__global__ __launch_bounds__(256) void k4_topk(
  const unsigned short* __restrict__ supR, const unsigned short* __restrict__ supI,
  const unsigned short* __restrict__ WcTb, const float* __restrict__ bcv,
  float* __restrict__ outg)
{
  __shared__ float msq[H_SZ];
  __shared__ int   redi[4];
  __shared__ int   sel_idx[64];
  __shared__ float sel_p[64];
  __shared__ int   cnt;
  __shared__ float ssum_sh;
  const int tid = threadIdx.x, lane = tid & 63, wid = tid >> 6;
  const int b = blockIdx.x;
  const size_t base = (size_t)b * H_SZ;

  if (tid < 64){ sel_p[tid] = 0.f; sel_idx[tid] = 0; }
  if (tid == 0) cnt = 0;

  float v[8]; unsigned int u[8];
  {
    s16x8 r = *(const s16x8*)&supR[base + tid*8];
    s16x8 qv = *(const s16x8*)&supI[base + tid*8];
    #pragma unroll
    for (int i = 0; i < 8; i++){
      float rf = bf2f((unsigned short)r[i]);
      float qf = bf2f((unsigned short)qv[i]);
      v[i] = rf*rf + qf*qf;
    }
  }
  #pragma unroll
  for (int i = 0; i < 8; i++){ msq[tid*8+i] = v[i]; u[i] = __float_as_uint(v[i]); }
  __syncthreads();

  unsigned int lo = 0u, hi = 0xFFFFFFFFu;
  for (int it = 0; it < 32; ++it){
    unsigned int mid = (unsigned int)(((unsigned long long)lo + (unsigned long long)hi + 1ull) >> 1);
    int c = 0;
    #pragma unroll
    for (int i = 0; i < 8; i++) c += (u[i] >= mid) ? 1 : 0;
    #pragma unroll
    for (int off = 32; off >= 1; off >>= 1) c += __shfl_down(c, off, 64);
    if (lane == 0) redi[wid] = c;
    __syncthreads();
    int total = redi[0]+redi[1]+redi[2]+redi[3];
    __syncthreads();
    if (total >= 64) lo = mid; else hi = mid - 1u;
  }
  const unsigned int V = lo;

  int cg = 0;
  #pragma unroll
  for (int i = 0; i < 8; i++) cg += (u[i] > V) ? 1 : 0;
  #pragma unroll
  for (int off = 32; off >= 1; off >>= 1) cg += __shfl_down(cg, off, 64);
  if (lane == 0) redi[wid] = cg;
  __syncthreads();
  const int ng = redi[0]+redi[1]+redi[2]+redi[3];
  const int kfill = 64 - ng;

  #pragma unroll
  for (int i = 0; i < 8; i++){
    if (u[i] > V){
      int ppos = atomicAdd(&cnt, 1);
      if (ppos < 64){ sel_idx[ppos] = tid*8 + i; sel_p[ppos] = v[i]; }
    }
  }
  __syncthreads();
  if (wid == 0){
    int taken = 0;
    for (int b2 = 0; b2 < H_SZ; b2 += 64){
      float val = msq[b2 + lane];
      bool eq = (__float_as_uint(val) == V);
      unsigned long long mk = __ballot(eq);
      int pre = __popcll(mk & ((1ull << lane) - 1ull));
      int dst = ng + taken + pre;
      if (eq && dst < 64){
        sel_idx[dst] = b2 + lane;
        sel_p [dst] = val;
      }
      taken += __popcll(mk);
      if (taken >= kfill) break;
    }
  }
  __syncthreads();
  if (wid == 0){
    float xx = sel_p[lane];
    #pragma unroll
    for (int off = 32; off >= 1; off >>= 1) xx += __shfl_down(xx, off, 64);
    if (lane == 0) ssum_sh = xx;
  }
  __syncthreads();
  const float invden = 1.f / (ssum_sh + EPSF);
  if (tid < 64) sel_p[tid] *= invden;
  __syncthreads();

  for (int c = tid; c < C_SZ; c += 256){
    float acc = bcv[c];
    #pragma unroll 8
    for (int k = 0; k < 64; k++) acc += sel_p[k] * bf2f(WcTb[(size_t)sel_idx[k]*C_SZ + c]);
    outg[(size_t)b*C_SZ + c] = acc;
  }
}

// ---------------- launch ----------------
extern "C" void kernel_launch(void* const* d_in, const int* in_sizes, int n_in,
                              void* d_out, int out_size, void* d_ws, size_t ws_size,
                              hipStream_t stream){
  (void)in_sizes; (void)n_in; (void)out_size;
  const float* x      = (const float*)d_in[0];
  const float* Wnet   = (const float*)d_in[1];
  const float* bnet   = (const float*)d_in[2];
  const float* phases = (const float*)d_in[3];
  const float* Wg     = (const float*)d_in[4];
  const float* bg     = (const float*)d_in[5];
  const float* Wc     = (const float*)d_in[6];
  const float* bc     = (const float*)d_in[7];
  float* out = (float*)d_out;

  char* p = (char*)d_ws;
  const size_t MB = 1024ull*1024ull;
  // phase A: xb (0..16MB) + Wnetb (16..48MB)
  // phase B: Wgb (0..8MB) + WcTb bf16 (8..12MB)   [xb region, dead by then]
  unsigned short* xb    = (unsigned short*)(p + 0);
  unsigned short* Wnetb = (unsigned short*)(p + 16*MB);
  unsigned short* Wgb   = (unsigned short*)(p + 0);
  unsigned short* WcTb  = (unsigned short*)(p + 8*MB);
  unsigned short* supR  = (unsigned short*)(p + 48*MB);
  unsigned short* supI  = (unsigned short*)(p + 80*MB);
  unsigned short* mag   = (unsigned short*)(p + 112*MB);
  unsigned short* G     = (unsigned short*)(p + 144*MB);

  size_t avail = (ws_size > 144*MB) ? (ws_size - 144*MB) : 0;
  long rows_cap = (long)(avail / ((size_t)N1 * 2));
  int chunk = (int)((rows_cap / 256) * 256);
  if (chunk > B_SZ) chunk = B_SZ;
  if (chunk < 256)  chunk = 256;

  cvt_bf16<<<(B_SZ*D_SZ/4 + 255)/256, 256, 0, stream>>>(x, xb, B_SZ*D_SZ/4);
  cvt_bf16<<<(N1*D_SZ/4 + 255)/256, 256, 0, stream>>>(Wnet, Wnetb, N1*D_SZ/4);

  for (int b0 = 0; b0 < B_SZ; b0 += chunk){
    int rows = (B_SZ - b0 < chunk) ? (B_SZ - b0) : chunk;
    gemm8<0><<<dim3(N1/256, rows/256), 512, 0, stream>>>(
        xb + (size_t)b0*D_SZ, Wnetb, rows, N1, D_SZ, bnet, G, nullptr, nullptr, nullptr);
    k2_superpose<<<rows, 256, 0, stream>>>(
        G, phases, supR + (size_t)b0*H_SZ, supI + (size_t)b0*H_SZ, mag + (size_t)b0*H_SZ);
  }

  // phase B
  cvt_bf16<<<(H_SZ*H_SZ/4 + 255)/256, 256, 0, stream>>>(Wg, Wgb, H_SZ*H_SZ/4);
  transpose_wc<<<(H_SZ*C_SZ + 255)/256, 256, 0, stream>>>(Wc, WcTb);

  gemm8<1><<<dim3(H_SZ/256, B_SZ/256), 512, 0, stream>>>(
      mag, Wgb, B_SZ, H_SZ, H_SZ, bg, nullptr, supR, supI, mag);
  gemm8<1><<<dim3(H_SZ/256, B_SZ/256), 512, 0, stream>>>(
      mag, Wgb, B_SZ, H_SZ, H_SZ, bg, nullptr, supR, supI, mag);

  k4_topk<<<B_SZ, 256, 0, stream>>>(supR, supI, WcTb, bc, out);
}